// Round 1
// baseline (193.761 us; speedup 1.0000x reference)
//
#include <hip/hip_runtime.h>

#define KE_CONST 14.3996454784255f

#define P2_SHIFT 15
#define P2_CHUNK 32768            // 128 KB LDS accumulator per chunk (scan)
#define SCAN_B2  64               // scan blocks per chunk
#define SCAN_THR 1024
#define MAXC     4
#define MAXE     16               // pair table up to 256 entries (4 KB LDS)
#define ELEM_CAP 131072           // 128 KB LDS elem table cap (dense)
#define DN_THR   1024
#define DN_BLOCKS 256
#define CNT_THR  1024

// ---------------- prep A: per-node element id (argmax over attrs) ----------------
__global__ void zbl_prep_elem(const float* __restrict__ node_attrs,
                              unsigned char* __restrict__ elem,
                              int n_nodes, int n_elem) {
    int n = blockIdx.x * blockDim.x + threadIdx.x;
    if (n >= n_nodes) return;
    const float* row = node_attrs + (size_t)n * n_elem;
    float best = row[0];
    int bi = 0;
    for (int i = 1; i < n_elem; ++i) {
        float v = row[i];
        if (v > best) { best = v; bi = i; }
    }
    elem[n] = (unsigned char)bi;
}

// ---------------- prep B: n_elem^2 pair table (+ zero bucket counters) ----------------
__global__ void zbl_prep_pairs(const int* __restrict__ atomic_numbers,
                               const float* __restrict__ covalent_radii,
                               float4* __restrict__ pair_tab,
                               unsigned* __restrict__ gcount,
                               int n_elem) {
    int t = threadIdx.x;
    if (t < MAXC) gcount[t] = 0u;
    int np = n_elem * n_elem;
    if (t >= np) return;
    int eu = t / n_elem;
    int ev = t - eu * n_elem;
    int Zu = atomic_numbers[eu];
    int Zv = atomic_numbers[ev];
    float zu = (float)Zu, zv = (float)Zv;
    float inv_a = (__powf(zu, 0.3f) + __powf(zv, 0.3f)) * (1.0f / (0.4543f * 0.529f));
    float kezz  = 0.5f * KE_CONST * zu * zv;
    float rmax  = covalent_radii[Zu] + covalent_radii[Zv];
    pair_tab[t] = make_float4(inv_a, kezz, rmax, 1.0f / rmax);
}

// ---------------- count pass: per-block chunk histogram + global bucket reservation ----
#define CNT4(V)                                                         \
    { unsigned cc;                                                      \
      cc = ((unsigned)(V).x) >> P2_SHIFT; c0 += (cc==0); c1 += (cc==1); c2 += (cc==2); c3 += (cc==3); \
      cc = ((unsigned)(V).y) >> P2_SHIFT; c0 += (cc==0); c1 += (cc==1); c2 += (cc==2); c3 += (cc==3); \
      cc = ((unsigned)(V).z) >> P2_SHIFT; c0 += (cc==0); c1 += (cc==1); c2 += (cc==2); c3 += (cc==3); \
      cc = ((unsigned)(V).w) >> P2_SHIFT; c0 += (cc==0); c1 += (cc==1); c2 += (cc==2); c3 += (cc==3); }

__global__ __launch_bounds__(CNT_THR)
void zbl_count(const int* __restrict__ ei,
               unsigned* __restrict__ gcount,
               unsigned* __restrict__ blkpos,
               int n_edges) {
    __shared__ unsigned h[MAXC];
    if (threadIdx.x < MAXC) h[threadIdx.x] = 0u;
    __syncthreads();

    long long e0 = (((long long)blockIdx.x * n_edges) / DN_BLOCKS) & ~3LL;
    long long e1 = (blockIdx.x == DN_BLOCKS - 1)
                     ? (long long)n_edges
                     : ((((long long)(blockIdx.x + 1) * n_edges) / DN_BLOCKS) & ~3LL);
    const int* r = ei + n_edges;
    unsigned c0 = 0, c1 = 0, c2 = 0, c3 = 0;

    const long long T4 = (long long)CNT_THR * 4;
    long long vend  = e1 & ~3LL;
    long long niter = (e1 - e0) / (T4 * 4);
    long long base  = e0 + (long long)threadIdx.x * 4;
    for (long long i = 0; i < niter; ++i, base += T4 * 4) {
        int4 a = *(const int4*)(r + base);
        int4 b = *(const int4*)(r + base + T4);
        int4 c = *(const int4*)(r + base + 2 * T4);
        int4 d = *(const int4*)(r + base + 3 * T4);
        CNT4(a); CNT4(b); CNT4(c); CNT4(d);
    }
    long long rem0 = e0 + niter * T4 * 4;
    for (long long b4 = rem0 + (long long)threadIdx.x * 4; b4 + 4 <= vend; b4 += T4) {
        int4 a = *(const int4*)(r + b4);
        CNT4(a);
    }
    for (long long e = vend + threadIdx.x; e < e1; e += CNT_THR) {
        unsigned cc = ((unsigned)r[e]) >> P2_SHIFT;
        c0 += (cc == 0); c1 += (cc == 1); c2 += (cc == 2); c3 += (cc == 3);
    }

    atomicAdd(&h[0], c0); atomicAdd(&h[1], c1);
    atomicAdd(&h[2], c2); atomicAdd(&h[3], c3);
    __syncthreads();
    if (threadIdx.x < MAXC)
        blkpos[blockIdx.x * MAXC + threadIdx.x] =
            atomicAdd(&gcount[threadIdx.x], h[threadIdx.x]);
}

// ---------------- per-edge bf16 value from pair-table entry ----------------
__device__ __forceinline__ unsigned enc_val16(float xv, const float4& p) {
    float t = xv * p.x;
    float phi = 0.1818f  * __expf(-3.2f    * t)
              + 0.5099f  * __expf(-0.9423f * t)
              + 0.2802f  * __expf(-0.4028f * t)
              + 0.02817f * __expf(-0.2016f * t);
    float rr = xv * p.w;
    float r2 = rr * rr;
    float r6 = r2 * r2 * r2;
    float env = 1.0f - 28.0f * r6 + 48.0f * r6 * rr - 21.0f * r6 * r2;
    float val = fmaxf(p.y * phi / xv * env, 0.0f);     // clamp r->1 cancellation negatives
    unsigned e = (__float_as_uint(val) + 0x8000u) >> 16;   // round-to-nearest bf16
    return (xv < p.z) ? e : 0u;
}

// ---------------- pass 1: dense compute -> chunk-bucketed scatter ----------------
// Word layout (bucketed, chunk implied by bucket): [31] unused, [30:16] local node
// id within chunk, [15:0] bf16 value bits.
#define SCATTER(RW, XV, PP)                                                   \
    { unsigned rr_  = (unsigned)(RW);                                         \
      unsigned ccx  = rr_ >> P2_SHIFT;                                        \
      unsigned w_   = ((rr_ & (P2_CHUNK - 1)) << 16) | enc_val16((XV), (PP)); \
      unsigned sb_  = (ccx == 0) ? seg0 : (ccx == 1) ? seg1                   \
                    : (ccx == 2) ? seg2 : seg3;                               \
      unsigned pos_ = atomicAdd(&cur[ccx], 1u);                               \
      packedB[(size_t)sb_ + pos_] = w_; }

__global__ __launch_bounds__(DN_THR)
void zbl_dense_lds(const float* __restrict__ x,
                   const int* __restrict__ ei,
                   const unsigned char* __restrict__ elem_g,
                   const float4* __restrict__ pair_tab,
                   const unsigned* __restrict__ gcount,
                   const unsigned* __restrict__ blkpos,
                   unsigned* __restrict__ packedB,
                   int n_edges, int n_elem, int n_nodes) {
    __shared__ __align__(16) unsigned char elem[ELEM_CAP];
    __shared__ float4 pt[MAXE * MAXE];
    __shared__ unsigned cur[MAXC];

    if (threadIdx.x < MAXC) cur[threadIdx.x] = 0u;
    int np = n_elem * n_elem;
    for (int i = threadIdx.x; i < np; i += DN_THR) pt[i] = pair_tab[i];
    int nwords = (n_nodes + 15) >> 4;
    const uint4* eg4 = (const uint4*)elem_g;
    uint4* el4 = (uint4*)elem;
    for (int i = threadIdx.x; i < nwords; i += DN_THR) el4[i] = eg4[i];

    // global bucket bases: cstart[c] + this block's reserved offset
    unsigned g0 = gcount[0], g1 = gcount[1], g2 = gcount[2];
    unsigned seg0 = blkpos[blockIdx.x * MAXC + 0];
    unsigned seg1 = g0 + blkpos[blockIdx.x * MAXC + 1];
    unsigned seg2 = g0 + g1 + blkpos[blockIdx.x * MAXC + 2];
    unsigned seg3 = g0 + g1 + g2 + blkpos[blockIdx.x * MAXC + 3];
    __syncthreads();

    long long e0 = (((long long)blockIdx.x * n_edges) / DN_BLOCKS) & ~3LL;
    long long e1 = (blockIdx.x == DN_BLOCKS - 1)
                     ? (long long)n_edges
                     : ((((long long)(blockIdx.x + 1) * n_edges) / DN_BLOCKS) & ~3LL);
    long long vend = e1 & ~3LL;

    for (long long b = e0 + (long long)threadIdx.x * 4; b + 4 <= vend;
         b += (long long)DN_THR * 4) {
        int4   s4 = *(const int4*)(ei + b);
        int4   r4 = *(const int4*)(ei + n_edges + b);
        float4 x4 = *(const float4*)(x + b);
        unsigned es0 = elem[s4.x], es1 = elem[s4.y], es2 = elem[s4.z], es3 = elem[s4.w];
        unsigned er0 = elem[r4.x], er1 = elem[r4.y], er2 = elem[r4.z], er3 = elem[r4.w];
        float4 p0 = pt[es0 * n_elem + er0];
        float4 p1 = pt[es1 * n_elem + er1];
        float4 p2 = pt[es2 * n_elem + er2];
        float4 p3 = pt[es3 * n_elem + er3];
        SCATTER(r4.x, x4.x, p0);
        SCATTER(r4.y, x4.y, p1);
        SCATTER(r4.z, x4.z, p2);
        SCATTER(r4.w, x4.w, p3);
    }
    for (long long e = vend + threadIdx.x; e < e1; e += DN_THR) {
        int r = ei[n_edges + e];
        float4 p = pt[elem[ei[e]] * n_elem + elem[r]];
        float xv = x[e];
        SCATTER(r, xv, p);
    }
}

// ---------------- pass 2: bucketed scan — each word read once, all lanes active ----
#define ACC1(W) atomicAdd(&acc[(W) >> 16], __uint_as_float(((W) & 0xFFFFu) << 16))
#define ACC4(Q) { ACC1((Q).x); ACC1((Q).y); ACC1((Q).z); ACC1((Q).w); }

__global__ __launch_bounds__(SCAN_THR)
void zbl_scan_b(const unsigned* __restrict__ packedB,
                const unsigned* __restrict__ gcount,
                float* __restrict__ partial,
                int n_edges) {
    unsigned c = blockIdx.x >> 6;            // SCAN_B2 = 64
    int      j = blockIdx.x & (SCAN_B2 - 1);

    __shared__ __align__(16) float acc[P2_CHUNK];
    for (int i = threadIdx.x * 4; i < P2_CHUNK; i += SCAN_THR * 4)
        *(float4*)&acc[i] = make_float4(0.f, 0.f, 0.f, 0.f);

    unsigned g0 = gcount[0], g1 = gcount[1], g2 = gcount[2], g3 = gcount[3];
    long long cst = (c == 0) ? 0LL
                  : (c == 1) ? (long long)g0
                  : (c == 2) ? (long long)g0 + g1
                             : (long long)g0 + g1 + g2;
    long long cnt = (c == 0) ? (long long)g0
                  : (c == 1) ? (long long)g1
                  : (c == 2) ? (long long)g2 : (long long)g3;
    long long s = cst + cnt * j / SCAN_B2;
    long long e = cst + cnt * (j + 1) / SCAN_B2;
    __syncthreads();

    long long va = (s + 3) & ~3LL; if (va > e) va = e;   // first 16B-aligned word
    long long ve = e & ~3LL;       if (ve < va) ve = va;

    for (long long i = s + threadIdx.x; i < va; i += SCAN_THR) {
        unsigned w = packedB[i]; ACC1(w);
    }
    const long long T4 = (long long)SCAN_THR * 4;
    long long niter = (ve - va) / (T4 * 4);
    long long base  = va + (long long)threadIdx.x * 4;
    for (long long i = 0; i < niter; ++i, base += T4 * 4) {
        uint4 q0 = *(const uint4*)(packedB + base);
        uint4 q1 = *(const uint4*)(packedB + base + T4);
        uint4 q2 = *(const uint4*)(packedB + base + 2 * T4);
        uint4 q3 = *(const uint4*)(packedB + base + 3 * T4);
        ACC4(q0); ACC4(q1); ACC4(q2); ACC4(q3);
    }
    long long rem0 = va + niter * T4 * 4;
    for (long long b = rem0 + (long long)threadIdx.x * 4; b + 4 <= ve; b += T4) {
        uint4 q = *(const uint4*)(packedB + b);
        ACC4(q);
    }
    for (long long i = ve + threadIdx.x; i < e; i += SCAN_THR) {
        unsigned w = packedB[i]; ACC1(w);
    }

    __syncthreads();
    float* pp = partial + (size_t)blockIdx.x * P2_CHUNK;
    for (int i = threadIdx.x * 4; i < P2_CHUNK; i += SCAN_THR * 4)
        *(float4*)(pp + i) = *(const float4*)&acc[i];
}

// ---------------- pass 3: reduce SCAN_B2 partials per node, overwrite out ----------------
__global__ void zbl_reduce(const float* __restrict__ partial,
                           float* __restrict__ out,
                           int n_nodes) {
    int i = blockIdx.x * blockDim.x + threadIdx.x;
    if (i >= n_nodes) return;
    int c  = i >> P2_SHIFT;
    int li = i & (P2_CHUNK - 1);
    const float* p = partial + ((size_t)c * SCAN_B2) * P2_CHUNK + li;
    float s0 = 0.f, s1 = 0.f, s2 = 0.f, s3 = 0.f;
    #pragma unroll
    for (int j = 0; j < SCAN_B2; j += 4) {
        s0 += p[(size_t)(j + 0) * P2_CHUNK];
        s1 += p[(size_t)(j + 1) * P2_CHUNK];
        s2 += p[(size_t)(j + 2) * P2_CHUNK];
        s3 += p[(size_t)(j + 3) * P2_CHUNK];
    }
    out[i] = (s0 + s1) + (s2 + s3);
}

// ================= fallback path: node float4 table + direct device atomics =================
__global__ void zbl_node_prep(const float* __restrict__ node_attrs,
                              const int* __restrict__ atomic_numbers,
                              const float* __restrict__ covalent_radii,
                              float4* __restrict__ node_data,
                              float* __restrict__ out_zero,
                              int n_nodes, int n_elem) {
    int n = blockIdx.x * blockDim.x + threadIdx.x;
    if (n >= n_nodes) return;
    const float* row = node_attrs + (size_t)n * n_elem;
    float best = row[0];
    int bi = 0;
    for (int i = 1; i < n_elem; ++i) {
        float v = row[i];
        if (v > best) { best = v; bi = i; }
    }
    int Z = atomic_numbers[bi];
    float zf = (float)Z;
    node_data[n] = make_float4(zf, __powf(zf, 0.3f), covalent_radii[Z], 0.0f);
    out_zero[n] = 0.0f;
}

__global__ void zbl_edge_atomic(const float* __restrict__ x,
                                const int* __restrict__ edge_index,
                                const float4* __restrict__ node_data,
                                float* __restrict__ out,
                                int n_edges) {
    int e = blockIdx.x * blockDim.x + threadIdx.x;
    if (e >= n_edges) return;
    int snd = edge_index[e];
    int r = edge_index[n_edges + e];
    float xv = x[e];
    float4 du = node_data[snd];
    float4 dv = node_data[r];
    float rmax = du.z + dv.z;
    if (xv >= rmax) return;
    const float inv_a_pref = 1.0f / (0.4543f * 0.529f);
    float t = xv * (du.y + dv.y) * inv_a_pref;
    float phi = 0.1818f  * __expf(-3.2f    * t)
              + 0.5099f  * __expf(-0.9423f * t)
              + 0.2802f  * __expf(-0.4028f * t)
              + 0.02817f * __expf(-0.2016f * t);
    float v = KE_CONST * du.x * dv.x * phi / xv;
    float rr = xv / rmax;
    float r2 = rr * rr;
    float r6 = r2 * r2 * r2;
    float env = 1.0f - 28.0f * r6 + 48.0f * r6 * rr - 21.0f * r6 * r2;
    atomicAdd(&out[r], 0.5f * v * env);
}

extern "C" void kernel_launch(void* const* d_in, const int* in_sizes, int n_in,
                              void* d_out, int out_size, void* d_ws, size_t ws_size,
                              hipStream_t stream) {
    const float* x              = (const float*)d_in[0];
    const float* node_attrs     = (const float*)d_in[1];
    const int*   edge_index     = (const int*)d_in[2];
    const int*   atomic_numbers = (const int*)d_in[3];
    const float* covalent_radii = (const float*)d_in[4];
    float* out = (float*)d_out;

    int n_edges = in_sizes[0];
    int n_elem  = in_sizes[3];
    int n_nodes = in_sizes[1] / n_elem;

    int C = (n_nodes + P2_CHUNK - 1) >> P2_SHIFT;
    size_t elem_bytes   = (((size_t)n_nodes) + 255) & ~(size_t)255;
    size_t pair_bytes   = ((size_t)MAXE * MAXE * sizeof(float4) + 255) & ~(size_t)255;
    size_t meta_bytes   = (((size_t)(MAXC + DN_BLOCKS * MAXC) * 4) + 255) & ~(size_t)255;
    size_t packed_bytes = (((size_t)n_edges * sizeof(unsigned)) + 255) & ~(size_t)255;
    size_t part_bytes   = (size_t)C * SCAN_B2 * P2_CHUNK * sizeof(float);
    bool fast = (C >= 1) && (C <= MAXC) && (n_nodes <= ELEM_CAP) &&
                (n_elem >= 1) && (n_elem <= MAXE) && ((n_edges & 3) == 0) &&
                (ws_size >= elem_bytes + pair_bytes + meta_bytes + packed_bytes + part_bytes);

    if (fast) {
        unsigned char* elem     = (unsigned char*)d_ws;
        float4*        pair_tab = (float4*)((char*)d_ws + elem_bytes);
        unsigned*      gcount   = (unsigned*)((char*)d_ws + elem_bytes + pair_bytes);
        unsigned*      blkpos   = gcount + 8;   // 32B past gcount, within meta block
        unsigned*      packedB  = (unsigned*)((char*)d_ws + elem_bytes + pair_bytes + meta_bytes);
        float*         part     = (float*)((char*)d_ws + elem_bytes + pair_bytes + meta_bytes + packed_bytes);

        zbl_prep_pairs<<<1, 256, 0, stream>>>(
            atomic_numbers, covalent_radii, pair_tab, gcount, n_elem);
        zbl_prep_elem<<<(n_nodes + 255) / 256, 256, 0, stream>>>(
            node_attrs, elem, n_nodes, n_elem);

        zbl_count<<<DN_BLOCKS, CNT_THR, 0, stream>>>(
            edge_index, gcount, blkpos, n_edges);

        zbl_dense_lds<<<DN_BLOCKS, DN_THR, 0, stream>>>(
            x, edge_index, elem, pair_tab, gcount, blkpos, packedB,
            n_edges, n_elem, n_nodes);

        zbl_scan_b<<<C * SCAN_B2, SCAN_THR, 0, stream>>>(packedB, gcount, part, n_edges);

        zbl_reduce<<<(n_nodes + 255) / 256, 256, 0, stream>>>(part, out, n_nodes);
        return;
    }

    // fallback: node table + plain device atomics
    float4* node_data = (float4*)d_ws;
    zbl_node_prep<<<(n_nodes + 255) / 256, 256, 0, stream>>>(
        node_attrs, atomic_numbers, covalent_radii, node_data,
        out, n_nodes, n_elem);
    zbl_edge_atomic<<<(n_edges + 255) / 256, 256, 0, stream>>>(
        x, edge_index, node_data, out, n_edges);
}